// Round 12
// baseline (342.512 us; speedup 1.0000x reference)
//
#include <hip/hip_runtime.h>
#include <hip/hip_bf16.h>

typedef unsigned short u16;
typedef __bf16 bf16x8 __attribute__((ext_vector_type(8)));
typedef float f32x4 __attribute__((ext_vector_type(4)));

#define DEV static __device__ __forceinline__

// ---------- helpers ----------
DEV u16 f2b(float f){                       // fp32 -> bf16 (RNE)
  union { float f; unsigned u; } v; v.f = f;
  unsigned r = (v.u + 0x7FFFu + ((v.u >> 16) & 1u)) >> 16;
  return (u16)r;
}

DEV unsigned pack2(float lo, float hi){     // 2 f32 -> packed bf16x2 (RNE), lo in [15:0]
  __hip_bfloat162 h = __float22bfloat162_rn(float2{lo, hi});
  union { __hip_bfloat162 h; unsigned u; } c; c.h = h;
  return c.u;
}

DEV unsigned pack_trunc(float lo, float hi){ // 2 f32 -> packed bf16x2 (truncate): 1 v_perm_b32
  union { float f; unsigned u; } a, b; a.f = lo; b.f = hi;
  return __builtin_amdgcn_perm(b.u, a.u, 0x07060302u);
}

DEV void gload16(const void* g, void* l){   // async global->LDS, 16B/lane
  __builtin_amdgcn_global_load_lds((const __attribute__((address_space(1))) void*)g,
                                   (__attribute__((address_space(3))) void*)l, 16, 0, 0);
}

DEV f32x4 mfma16(bf16x8 a, bf16x8 b, f32x4 c){
  return __builtin_amdgcn_mfma_f32_16x16x32_bf16(a, b, c, 0, 0, 0);
}

// ---------- fp32 -> bf16 convert (x) ----------
__global__ void cvt_kernel(const float* __restrict__ src, u16* __restrict__ dst, int n4){
  int i = blockIdx.x * 256 + threadIdx.x;
  if (i < n4){
    float4 v = reinterpret_cast<const float4*>(src)[i];
    ushort4 o;
    o.x = f2b(v.x); o.y = f2b(v.y); o.z = f2b(v.z); o.w = f2b(v.w);
    reinterpret_cast<ushort4*>(dst)[i] = o;
  }
}

// ---------- fp32 -> bf16 convert (4 weights, one dispatch) ----------
__global__ void cvt4_kernel(const float* __restrict__ w0, const float* __restrict__ w1,
                            const float* __restrict__ w2, const float* __restrict__ w3,
                            u16* __restrict__ o0, u16* __restrict__ o1,
                            u16* __restrict__ o2, u16* __restrict__ o3){
  int r = blockIdx.x >> 10;
  int i = (blockIdx.x & 1023) * 256 + threadIdx.x;
  const float* s = (r == 0) ? w0 : (r == 1) ? w1 : (r == 2) ? w2 : w3;
  u16*         d = (r == 0) ? o0 : (r == 1) ? o1 : (r == 2) ? o2 : o3;
  float4 v = reinterpret_cast<const float4*>(s)[i];
  ushort4 o;
  o.x = f2b(v.x); o.y = f2b(v.y); o.z = f2b(v.z); o.w = f2b(v.w);
  reinterpret_cast<ushort4*>(d)[i] = o;
}

// ---------- fused QKV GEMM: C[m,n] = sum_k x[m,k]*Wqkv[n,k], M=8192 N=3072 K=1024 ----------
__global__ __launch_bounds__(256, 2)
void gemm_qkv(const u16* __restrict__ A, const u16* __restrict__ B,
              u16* __restrict__ Qb, u16* __restrict__ Kb, u16* __restrict__ Vtb){
  __shared__ __align__(16) u16 lsA[128*64];
  __shared__ __align__(16) u16 lsB[128*64];
  const int tid  = threadIdx.x;
  const int lane = tid & 63, wid = tid >> 6;
  const int g = lane >> 4, c15 = lane & 15;
  const int m0 = blockIdx.x * 128, n0 = blockIdx.y * 128;
  const int wm = (wid >> 1) * 64, wn = (wid & 1) * 64;
  const f32x4 vzero = {0.f, 0.f, 0.f, 0.f};

  f32x4 acc[4][4];
#pragma unroll
  for (int mi = 0; mi < 4; ++mi)
#pragma unroll
    for (int ni = 0; ni < 4; ++ni) acc[mi][ni] = vzero;

  for (int kt = 0; kt < 16; ++kt){
    __syncthreads();
#pragma unroll
    for (int i = 0; i < 4; ++i){
      int c = i * 256 + tid;
      int row = c >> 3, gc = (c & 7) ^ (row & 7);
      gload16(A + ((size_t)(m0 + row) << 10) + (kt << 6) + (gc << 3), lsA + (size_t)c * 8);
    }
#pragma unroll
    for (int i = 0; i < 4; ++i){
      int c = i * 256 + tid;
      int row = c >> 3, gc = (c & 7) ^ (row & 7);
      gload16(B + ((size_t)(n0 + row) << 10) + (kt << 6) + (gc << 3), lsB + (size_t)c * 8);
    }
    __syncthreads();

    bf16x8 af[4][2], bf[4][2];
#pragma unroll
    for (int mi = 0; mi < 4; ++mi)
#pragma unroll
      for (int kk = 0; kk < 2; ++kk){
        int ra = wm + mi * 16 + c15;
        af[mi][kk] = *reinterpret_cast<const bf16x8*>(lsA + ra * 64 + ((((kk << 2) + g) ^ (ra & 7)) << 3));
        int rb = wn + mi * 16 + c15;
        bf[mi][kk] = *reinterpret_cast<const bf16x8*>(lsB + rb * 64 + ((((kk << 2) + g) ^ (rb & 7)) << 3));
      }
#pragma unroll
    for (int mi = 0; mi < 4; ++mi)
#pragma unroll
      for (int ni = 0; ni < 4; ++ni){
        acc[mi][ni] = mfma16(af[mi][0], bf[ni][0], acc[mi][ni]);
        acc[mi][ni] = mfma16(af[mi][1], bf[ni][1], acc[mi][ni]);
      }
  }

  const int reg = n0 >> 10;                   // 0:Q 1:K 2:V (wave-uniform)
#pragma unroll
  for (int mi = 0; mi < 4; ++mi)
#pragma unroll
    for (int ni = 0; ni < 4; ++ni){
      int mrow = m0 + wm + mi * 16 + g * 4;
      int ncolL = (n0 + wn + ni * 16 + c15) & 1023;
      int b = mrow >> 11, s = mrow & 2047;
      int h = ncolL >> 6, dk = ncolL & 63;
      if (reg < 2){
        const float sc = (reg == 0) ? 0.125f : 1.0f;
        u16* dst = (reg == 0 ? Qb : Kb) + (((size_t)(b * 16 + h) * 2048 + s) << 6) + dk;
#pragma unroll
        for (int r = 0; r < 4; ++r) dst[(size_t)r << 6] = f2b(acc[mi][ni][r] * sc);
      } else {
        ushort4 o;
        o.x = f2b(acc[mi][ni][0]); o.y = f2b(acc[mi][ni][1]);
        o.z = f2b(acc[mi][ni][2]); o.w = f2b(acc[mi][ni][3]);
        *reinterpret_cast<ushort4*>(Vtb + (((size_t)(b * 16 + h) * 64 + dk) << 11) + s) = o;
      }
    }
}

// ---------- O-projection GEMM: out[m,n] = sum_k O[m,k]*Wo[n,k] (fp32 out) ----------
__global__ __launch_bounds__(256, 2)
void gemm_out(const u16* __restrict__ A, const u16* __restrict__ B, float* __restrict__ Out){
  __shared__ __align__(16) u16 lsA[128*64];
  __shared__ __align__(16) u16 lsB[128*64];
  const int tid  = threadIdx.x;
  const int lane = tid & 63, wid = tid >> 6;
  const int g = lane >> 4, c15 = lane & 15;
  const int m0 = blockIdx.x * 128, n0 = blockIdx.y * 128;
  const int wm = (wid >> 1) * 64, wn = (wid & 1) * 64;
  const f32x4 vzero = {0.f, 0.f, 0.f, 0.f};

  f32x4 acc[4][4];
#pragma unroll
  for (int mi = 0; mi < 4; ++mi)
#pragma unroll
    for (int ni = 0; ni < 4; ++ni) acc[mi][ni] = vzero;

  for (int kt = 0; kt < 16; ++kt){
    __syncthreads();
#pragma unroll
    for (int i = 0; i < 4; ++i){              // A from [B,H,S,Dk]-layout O buffer; kt == head
      int c = i * 256 + tid;
      int row = c >> 3, gc = (c & 7) ^ (row & 7);
      int b = m0 >> 11, s = (m0 & 2047) + row;
      gload16(A + (((size_t)(b * 16 + kt) * 2048 + s) << 6) + (gc << 3), lsA + (size_t)c * 8);
    }
#pragma unroll
    for (int i = 0; i < 4; ++i){
      int c = i * 256 + tid;
      int row = c >> 3, gc = (c & 7) ^ (row & 7);
      gload16(B + ((size_t)(n0 + row) << 10) + (kt << 6) + (gc << 3), lsB + (size_t)c * 8);
    }
    __syncthreads();

    bf16x8 af[4][2], bf[4][2];
#pragma unroll
    for (int mi = 0; mi < 4; ++mi)
#pragma unroll
      for (int kk = 0; kk < 2; ++kk){
        int ra = wm + mi * 16 + c15;
        af[mi][kk] = *reinterpret_cast<const bf16x8*>(lsA + ra * 64 + ((((kk << 2) + g) ^ (ra & 7)) << 3));
        int rb = wn + mi * 16 + c15;
        bf[mi][kk] = *reinterpret_cast<const bf16x8*>(lsB + rb * 64 + ((((kk << 2) + g) ^ (rb & 7)) << 3));
      }
#pragma unroll
    for (int mi = 0; mi < 4; ++mi)
#pragma unroll
      for (int ni = 0; ni < 4; ++ni){
        acc[mi][ni] = mfma16(af[mi][0], bf[ni][0], acc[mi][ni]);
        acc[mi][ni] = mfma16(af[mi][1], bf[ni][1], acc[mi][ni]);
      }
  }

#pragma unroll
  for (int mi = 0; mi < 4; ++mi)
#pragma unroll
    for (int ni = 0; ni < 4; ++ni){
      int mrow = m0 + wm + mi * 16 + g * 4;
      int ncol = n0 + wn + ni * 16 + c15;
      float* dst = Out + (size_t)mrow * 1024 + ncol;
#pragma unroll
      for (int r = 0; r < 4; ++r) dst[(size_t)r << 10] = acc[mi][ni][r];
    }
}

// ---------- flash attention v12: LDS-free, barrier-free ----------
// K/V are L1/L2-resident (XCD head grouping): fragments load DIRECTLY global->reg.
// Addresses replicate the proven swizzle-identity mapping:
//   kf[ni][kk] = K [hb + (t*64+ni*16+c15)*64 + kk*32 + g*8]   (16B contiguous)
//   vf[di][kk] = Vt[hb + (di*16+c15)*2048 + t*64 + kk*32 + g*8]
// No __shared__, no __syncthreads: 4 waves/block fully independent.
__global__ __launch_bounds__(256, 4)
void attn_kernel(const u16* __restrict__ Q, const u16* __restrict__ K,
                 const u16* __restrict__ Vt, u16* __restrict__ O){
  const int tid  = threadIdx.x;
  const int lane = tid & 63;
  const int g = lane >> 4, c15 = lane & 15;
  const int bid  = blockIdx.x;
  const int head = (bid & 7) * 8 + ((bid >> 3) >> 4);   // XCD-grouped head
  const int qt   = (bid >> 3) & 15;
  const size_t hb = (size_t)head << 17;
  const int q0 = qt * 128 + (tid >> 6) * 32;
  const f32x4 vzero = {0.f, 0.f, 0.f, 0.f};

  const int srcA = c15 + ((lane & 16) << 1);
  const int srcB = srcA + 16;
  const bool hihalf = (lane >= 32);

  const u16* Kf = K  + hb + ((size_t)c15 << 6)  + g * 8;   // + (t*64+ni*16)*64 + kk*32
  const u16* Vf = Vt + hb + ((size_t)c15 << 11) + g * 8;   // + di*16*2048 + t*64 + kk*32

  bf16x8 qf[2][2];                              // Q hoisted (B-operand layout)
#pragma unroll
  for (int mi = 0; mi < 2; ++mi)
#pragma unroll
    for (int kk = 0; kk < 2; ++kk)
      qf[mi][kk] = *reinterpret_cast<const bf16x8*>(Q + hb + ((size_t)(q0 + mi*16 + c15) << 6) + kk*32 + g*8);

  union { unsigned u[4]; bf16x8 v; } ou;        // all-ones bf16 A-frag for row sums
  ou.u[0] = ou.u[1] = ou.u[2] = ou.u[3] = 0x3F803F80u;
  const bf16x8 ones = ou.v;

  f32x4 oaccT[2][4];
  float mrun[2], lrun[2];
#pragma unroll
  for (int mi = 0; mi < 2; ++mi){
#pragma unroll
    for (int di = 0; di < 4; ++di) oaccT[mi][di] = vzero;
    mrun[mi] = -1e30f; lrun[mi] = 0.f;
  }

  for (int t = 0; t < 32; ++t){
    // K fragments: direct global->reg (L1-hot: 4 blocks/CU share this head's stream)
    bf16x8 kf[4][2];
#pragma unroll
    for (int ni = 0; ni < 4; ++ni)
#pragma unroll
      for (int kk = 0; kk < 2; ++kk)
        kf[ni][kk] = *reinterpret_cast<const bf16x8*>(Kf + ((size_t)(t*64 + ni*16) << 6) + kk*32);

    f32x4 sacc[2][4];                           // S^T: lane c15=q, reg g*4+r = kv
    __builtin_amdgcn_s_setprio(1);
#pragma unroll
    for (int mi = 0; mi < 2; ++mi)
#pragma unroll
      for (int ni = 0; ni < 4; ++ni)
        sacc[mi][ni] = mfma16(kf[ni][1], qf[mi][1], mfma16(kf[ni][0], qf[mi][0], vzero));
    __builtin_amdgcn_s_setprio(0);

    // V fragments issued here: softmax (~400cy VALU) hides their L1/L2 latency
    bf16x8 vf[4][2];
#pragma unroll
    for (int di = 0; di < 4; ++di)
#pragma unroll
      for (int kk = 0; kk < 2; ++kk)
        vf[di][kk] = *reinterpret_cast<const bf16x8*>(Vf + ((size_t)(di*16) << 11) + t*64 + kk*32);

    // lane-local online softmax -> packed P in registers
    unsigned pk[2][4][2];
#pragma unroll
    for (int mi = 0; mi < 2; ++mi){
      float a0 = fmaxf(fmaxf(sacc[mi][0][0], sacc[mi][0][1]), sacc[mi][0][2]);
      float a1 = fmaxf(fmaxf(sacc[mi][0][3], sacc[mi][1][0]), sacc[mi][1][1]);
      float a2 = fmaxf(fmaxf(sacc[mi][1][2], sacc[mi][1][3]), sacc[mi][2][0]);
      float a3 = fmaxf(fmaxf(sacc[mi][2][1], sacc[mi][2][2]), sacc[mi][2][3]);
      float a4 = fmaxf(fmaxf(sacc[mi][3][0], sacc[mi][3][1]), sacc[mi][3][2]);
      float b0 = fmaxf(fmaxf(a0, a1), a2);
      float b1 = fmaxf(fmaxf(a3, a4), sacc[mi][3][3]);
      float mt = fmaxf(b0, b1);
      mt = fmaxf(mt, __shfl_xor(mt, 16, 64));
      mt = fmaxf(mt, __shfl_xor(mt, 32, 64));
      if (mt > mrun[mi]){                       // exact defer: skip rescale when no growth
        float f_ = __expf(mrun[mi] - mt);
        mrun[mi] = mt;
        lrun[mi] *= f_;
#pragma unroll
        for (int di = 0; di < 4; ++di) oaccT[mi][di] = oaccT[mi][di] * f_;
      }
      const float mn = mrun[mi];
#pragma unroll
      for (int ni = 0; ni < 4; ++ni){
        float p0 = __expf(sacc[mi][ni][0] - mn);
        float p1 = __expf(sacc[mi][ni][1] - mn);
        float p2 = __expf(sacc[mi][ni][2] - mn);
        float p3 = __expf(sacc[mi][ni][3] - mn);
        pk[mi][ni][0] = pack_trunc(p0, p1);
        pk[mi][ni][1] = pack_trunc(p2, p3);
      }
    }

    // in-register P redistribution: D-layout -> B-operand layout (2 shfl + select per u32)
    bf16x8 pf[2][2];
#pragma unroll
    for (int mi = 0; mi < 2; ++mi)
#pragma unroll
      for (int kk = 0; kk < 2; ++kk){
        union { unsigned u[4]; bf16x8 v; } pu;
#pragma unroll
        for (int w = 0; w < 4; ++w){
          const int p = w & 1;
          const int src = (w < 2) ? srcA : srcB;
          unsigned va = (unsigned)__shfl((int)pk[mi][2*kk    ][p], src, 64);
          unsigned vb = (unsigned)__shfl((int)pk[mi][2*kk + 1][p], src, 64);
          pu.u[w] = hihalf ? vb : va;
        }
        pf[mi][kk] = pu.v;
      }

    // row sums + PV on the MFMA pipe
    __builtin_amdgcn_s_setprio(1);
#pragma unroll
    for (int mi = 0; mi < 2; ++mi){
      f32x4 ls = mfma16(ones, pf[mi][0], vzero);
      ls = mfma16(ones, pf[mi][1], ls);
      lrun[mi] += ls[0];
    }
#pragma unroll
    for (int mi = 0; mi < 2; ++mi)
#pragma unroll
      for (int di = 0; di < 4; ++di){
        oaccT[mi][di] = mfma16(vf[di][0], pf[mi][0], oaccT[mi][di]);
        oaccT[mi][di] = mfma16(vf[di][1], pf[mi][1], oaccT[mi][di]);
      }
    __builtin_amdgcn_s_setprio(0);
  }

  // normalize + write O [B,H,S,Dk]; lane c15=q, dk = di*16+g*4+r (RNE pack)
#pragma unroll
  for (int mi = 0; mi < 2; ++mi){
    float inv = 1.f / lrun[mi];
    int q = q0 + mi*16 + c15;
#pragma unroll
    for (int di = 0; di < 4; ++di){
      unsigned lo = pack2(oaccT[mi][di][0] * inv, oaccT[mi][di][1] * inv);
      unsigned hi = pack2(oaccT[mi][di][2] * inv, oaccT[mi][di][3] * inv);
      *reinterpret_cast<uint2*>(O + hb + ((size_t)q << 6) + di*16 + g*4) = make_uint2(lo, hi);
    }
  }
}

// ---------- launch ----------
extern "C" void kernel_launch(void* const* d_in, const int* in_sizes, int n_in,
                              void* d_out, int out_size, void* d_ws, size_t ws_size,
                              hipStream_t stream){
  const float* x  = (const float*)d_in[0];
  const float* wq = (const float*)d_in[1];
  const float* wk = (const float*)d_in[2];
  const float* wv = (const float*)d_in[3];
  const float* wo = (const float*)d_in[4];
  float* out = (float*)d_out;
  char* ws = (char*)d_ws;
  u16* xb  = (u16*)(ws);                    // 16 MB  x bf16 [8192][1024]
  u16* wqb = (u16*)(ws + (16u << 20));      // 2 MB  } contiguous [3072][1024]
  u16* wkb = (u16*)(ws + (18u << 20));      // 2 MB  }
  u16* wvb = (u16*)(ws + (20u << 20));      // 2 MB  }
  u16* wob = (u16*)(ws + (22u << 20));      // 2 MB
  u16* Qb  = (u16*)(ws + (24u << 20));      // 16 MB [B,H,S,Dk] pre-scaled 1/8
  u16* Kb  = (u16*)(ws + (40u << 20));      // 16 MB [B,H,S,Dk]
  u16* Vtb = (u16*)(ws + (56u << 20));      // 16 MB [B,H,Dk,S]
  u16* Ob  = (u16*)(ws + (72u << 20));      // 16 MB [B,H,S,Dk]

  cvt_kernel<<<8192, 256, 0, stream>>>(x, xb, 2097152);
  cvt4_kernel<<<4096, 256, 0, stream>>>(wq, wk, wv, wo, wqb, wkb, wvb, wob);
  gemm_qkv<<<dim3(64, 24), 256, 0, stream>>>(xb, wqb, Qb, Kb, Vtb);
  attn_kernel<<<1024, 256, 0, stream>>>(Qb, Kb, Vtb, Ob);
  gemm_out<<<dim3(64, 8), 256, 0, stream>>>(Ob, wob, out);
}

// Round 13
// 203.550 us; speedup vs baseline: 1.6827x; 1.6827x over previous
//
#include <hip/hip_runtime.h>
#include <hip/hip_bf16.h>

typedef unsigned short u16;
typedef __bf16 bf16x8 __attribute__((ext_vector_type(8)));
typedef float f32x4 __attribute__((ext_vector_type(4)));

#define DEV static __device__ __forceinline__

// ---------- helpers ----------
DEV u16 f2b(float f){                       // fp32 -> bf16 (RNE)
  union { float f; unsigned u; } v; v.f = f;
  unsigned r = (v.u + 0x7FFFu + ((v.u >> 16) & 1u)) >> 16;
  return (u16)r;
}

DEV unsigned pack2(float lo, float hi){     // 2 f32 -> packed bf16x2 (RNE), lo in [15:0]
  __hip_bfloat162 h = __float22bfloat162_rn(float2{lo, hi});
  union { __hip_bfloat162 h; unsigned u; } c; c.h = h;
  return c.u;
}

DEV unsigned pack_trunc(float lo, float hi){ // 2 f32 -> packed bf16x2 (truncate): 1 v_perm_b32
  union { float f; unsigned u; } a, b; a.f = lo; b.f = hi;
  return __builtin_amdgcn_perm(b.u, a.u, 0x07060302u);
}

DEV void gload16(const void* g, void* l){   // async global->LDS, 16B/lane
  __builtin_amdgcn_global_load_lds((const __attribute__((address_space(1))) void*)g,
                                   (__attribute__((address_space(3))) void*)l, 16, 0, 0);
}

DEV f32x4 mfma16(bf16x8 a, bf16x8 b, f32x4 c){
  return __builtin_amdgcn_mfma_f32_16x16x32_bf16(a, b, c, 0, 0, 0);
}

// ---------- fp32 -> bf16 convert (x) ----------
__global__ void cvt_kernel(const float* __restrict__ src, u16* __restrict__ dst, int n4){
  int i = blockIdx.x * 256 + threadIdx.x;
  if (i < n4){
    float4 v = reinterpret_cast<const float4*>(src)[i];
    ushort4 o;
    o.x = f2b(v.x); o.y = f2b(v.y); o.z = f2b(v.z); o.w = f2b(v.w);
    reinterpret_cast<ushort4*>(dst)[i] = o;
  }
}

// ---------- fp32 -> bf16 convert (4 weights, one dispatch) ----------
__global__ void cvt4_kernel(const float* __restrict__ w0, const float* __restrict__ w1,
                            const float* __restrict__ w2, const float* __restrict__ w3,
                            u16* __restrict__ o0, u16* __restrict__ o1,
                            u16* __restrict__ o2, u16* __restrict__ o3){
  int r = blockIdx.x >> 10;
  int i = (blockIdx.x & 1023) * 256 + threadIdx.x;
  const float* s = (r == 0) ? w0 : (r == 1) ? w1 : (r == 2) ? w2 : w3;
  u16*         d = (r == 0) ? o0 : (r == 1) ? o1 : (r == 2) ? o2 : o3;
  float4 v = reinterpret_cast<const float4*>(s)[i];
  ushort4 o;
  o.x = f2b(v.x); o.y = f2b(v.y); o.z = f2b(v.z); o.w = f2b(v.w);
  reinterpret_cast<ushort4*>(d)[i] = o;
}

// ---------- fused QKV GEMM: C[m,n] = sum_k x[m,k]*Wqkv[n,k], M=8192 N=3072 K=1024 ----------
__global__ __launch_bounds__(256, 2)
void gemm_qkv(const u16* __restrict__ A, const u16* __restrict__ B,
              u16* __restrict__ Qb, u16* __restrict__ Kb, u16* __restrict__ Vtb){
  __shared__ __align__(16) u16 lsA[128*64];
  __shared__ __align__(16) u16 lsB[128*64];
  const int tid  = threadIdx.x;
  const int lane = tid & 63, wid = tid >> 6;
  const int g = lane >> 4, c15 = lane & 15;
  const int m0 = blockIdx.x * 128, n0 = blockIdx.y * 128;
  const int wm = (wid >> 1) * 64, wn = (wid & 1) * 64;
  const f32x4 vzero = {0.f, 0.f, 0.f, 0.f};

  f32x4 acc[4][4];
#pragma unroll
  for (int mi = 0; mi < 4; ++mi)
#pragma unroll
    for (int ni = 0; ni < 4; ++ni) acc[mi][ni] = vzero;

  for (int kt = 0; kt < 16; ++kt){
    __syncthreads();
#pragma unroll
    for (int i = 0; i < 4; ++i){
      int c = i * 256 + tid;
      int row = c >> 3, gc = (c & 7) ^ (row & 7);
      gload16(A + ((size_t)(m0 + row) << 10) + (kt << 6) + (gc << 3), lsA + (size_t)c * 8);
    }
#pragma unroll
    for (int i = 0; i < 4; ++i){
      int c = i * 256 + tid;
      int row = c >> 3, gc = (c & 7) ^ (row & 7);
      gload16(B + ((size_t)(n0 + row) << 10) + (kt << 6) + (gc << 3), lsB + (size_t)c * 8);
    }
    __syncthreads();

    bf16x8 af[4][2], bf[4][2];
#pragma unroll
    for (int mi = 0; mi < 4; ++mi)
#pragma unroll
      for (int kk = 0; kk < 2; ++kk){
        int ra = wm + mi * 16 + c15;
        af[mi][kk] = *reinterpret_cast<const bf16x8*>(lsA + ra * 64 + ((((kk << 2) + g) ^ (ra & 7)) << 3));
        int rb = wn + mi * 16 + c15;
        bf[mi][kk] = *reinterpret_cast<const bf16x8*>(lsB + rb * 64 + ((((kk << 2) + g) ^ (rb & 7)) << 3));
      }
#pragma unroll
    for (int mi = 0; mi < 4; ++mi)
#pragma unroll
      for (int ni = 0; ni < 4; ++ni){
        acc[mi][ni] = mfma16(af[mi][0], bf[ni][0], acc[mi][ni]);
        acc[mi][ni] = mfma16(af[mi][1], bf[ni][1], acc[mi][ni]);
      }
  }

  const int reg = n0 >> 10;                   // 0:Q 1:K 2:V (wave-uniform)
#pragma unroll
  for (int mi = 0; mi < 4; ++mi)
#pragma unroll
    for (int ni = 0; ni < 4; ++ni){
      int mrow = m0 + wm + mi * 16 + g * 4;
      int ncolL = (n0 + wn + ni * 16 + c15) & 1023;
      int b = mrow >> 11, s = mrow & 2047;
      int h = ncolL >> 6, dk = ncolL & 63;
      if (reg < 2){
        const float sc = (reg == 0) ? 0.125f : 1.0f;
        u16* dst = (reg == 0 ? Qb : Kb) + (((size_t)(b * 16 + h) * 2048 + s) << 6) + dk;
#pragma unroll
        for (int r = 0; r < 4; ++r) dst[(size_t)r << 6] = f2b(acc[mi][ni][r] * sc);
      } else {
        ushort4 o;
        o.x = f2b(acc[mi][ni][0]); o.y = f2b(acc[mi][ni][1]);
        o.z = f2b(acc[mi][ni][2]); o.w = f2b(acc[mi][ni][3]);
        *reinterpret_cast<ushort4*>(Vtb + (((size_t)(b * 16 + h) * 64 + dk) << 11) + s) = o;
      }
    }
}

// ---------- O-projection GEMM: out[m,n] = sum_k O[m,k]*Wo[n,k] (fp32 out) ----------
__global__ __launch_bounds__(256, 2)
void gemm_out(const u16* __restrict__ A, const u16* __restrict__ B, float* __restrict__ Out){
  __shared__ __align__(16) u16 lsA[128*64];
  __shared__ __align__(16) u16 lsB[128*64];
  const int tid  = threadIdx.x;
  const int lane = tid & 63, wid = tid >> 6;
  const int g = lane >> 4, c15 = lane & 15;
  const int m0 = blockIdx.x * 128, n0 = blockIdx.y * 128;
  const int wm = (wid >> 1) * 64, wn = (wid & 1) * 64;
  const f32x4 vzero = {0.f, 0.f, 0.f, 0.f};

  f32x4 acc[4][4];
#pragma unroll
  for (int mi = 0; mi < 4; ++mi)
#pragma unroll
    for (int ni = 0; ni < 4; ++ni) acc[mi][ni] = vzero;

  for (int kt = 0; kt < 16; ++kt){
    __syncthreads();
#pragma unroll
    for (int i = 0; i < 4; ++i){              // A from [B,H,S,Dk]-layout O buffer; kt == head
      int c = i * 256 + tid;
      int row = c >> 3, gc = (c & 7) ^ (row & 7);
      int b = m0 >> 11, s = (m0 & 2047) + row;
      gload16(A + (((size_t)(b * 16 + kt) * 2048 + s) << 6) + (gc << 3), lsA + (size_t)c * 8);
    }
#pragma unroll
    for (int i = 0; i < 4; ++i){
      int c = i * 256 + tid;
      int row = c >> 3, gc = (c & 7) ^ (row & 7);
      gload16(B + ((size_t)(n0 + row) << 10) + (kt << 6) + (gc << 3), lsB + (size_t)c * 8);
    }
    __syncthreads();

    bf16x8 af[4][2], bf[4][2];
#pragma unroll
    for (int mi = 0; mi < 4; ++mi)
#pragma unroll
      for (int kk = 0; kk < 2; ++kk){
        int ra = wm + mi * 16 + c15;
        af[mi][kk] = *reinterpret_cast<const bf16x8*>(lsA + ra * 64 + ((((kk << 2) + g) ^ (ra & 7)) << 3));
        int rb = wn + mi * 16 + c15;
        bf[mi][kk] = *reinterpret_cast<const bf16x8*>(lsB + rb * 64 + ((((kk << 2) + g) ^ (rb & 7)) << 3));
      }
#pragma unroll
    for (int mi = 0; mi < 4; ++mi)
#pragma unroll
      for (int ni = 0; ni < 4; ++ni){
        acc[mi][ni] = mfma16(af[mi][0], bf[ni][0], acc[mi][ni]);
        acc[mi][ni] = mfma16(af[mi][1], bf[ni][1], acc[mi][ni]);
      }
  }

#pragma unroll
  for (int mi = 0; mi < 4; ++mi)
#pragma unroll
    for (int ni = 0; ni < 4; ++ni){
      int mrow = m0 + wm + mi * 16 + g * 4;
      int ncol = n0 + wn + ni * 16 + c15;
      float* dst = Out + (size_t)mrow * 1024 + ncol;
#pragma unroll
      for (int r = 0; r < 4; ++r) dst[(size_t)r << 10] = acc[mi][ni][r];
    }
}

// ---------- flash attention (r10-proven): XCD head grouping + in-register P + LDS dbuf ----------
__global__ __launch_bounds__(256, 4)
void attn_kernel(const u16* __restrict__ Q, const u16* __restrict__ K,
                 const u16* __restrict__ Vt, u16* __restrict__ O){
  __shared__ __align__(16) u16 lsK[2][64*64];
  __shared__ __align__(16) u16 lsV[2][64*64];
  const int tid  = threadIdx.x;
  const int lane = tid & 63;
  const int g = lane >> 4, c15 = lane & 15;
  const int bid  = blockIdx.x;
  const int head = (bid & 7) * 8 + ((bid >> 3) >> 4);   // XCD-grouped head
  const int qt   = (bid >> 3) & 15;
  const size_t hb = (size_t)head << 17;
  const int q0 = qt * 128 + (tid >> 6) * 32;
  const f32x4 vzero = {0.f, 0.f, 0.f, 0.f};

  const int srcA = c15 + ((lane & 16) << 1);
  const int srcB = srcA + 16;
  const bool hihalf = (lane >= 32);

#define STAGE_T(tb, tt) do {                                                        \
    _Pragma("unroll")                                                               \
    for (int i_ = 0; i_ < 2; ++i_){                                                 \
      int c_ = i_ * 256 + tid;                                                      \
      int row_ = c_ >> 3, gc_ = (c_ & 7) ^ (row_ & 7);                              \
      gload16(K  + hb + ((size_t)((tt)*64 + row_) << 6) + (gc_ << 3), lsK[tb] + (size_t)c_ * 8); \
      gload16(Vt + hb + ((size_t)row_ << 11) + (tt)*64 + (gc_ << 3),  lsV[tb] + (size_t)c_ * 8); \
    }                                                                               \
  } while (0)

  bf16x8 qf[2][2];
#pragma unroll
  for (int mi = 0; mi < 2; ++mi)
#pragma unroll
    for (int kk = 0; kk < 2; ++kk)
      qf[mi][kk] = *reinterpret_cast<const bf16x8*>(Q + hb + ((size_t)(q0 + mi*16 + c15) << 6) + kk*32 + g*8);

  union { unsigned u[4]; bf16x8 v; } ou;
  ou.u[0] = ou.u[1] = ou.u[2] = ou.u[3] = 0x3F803F80u;
  const bf16x8 ones = ou.v;

  f32x4 oaccT[2][4];
  float mrun[2], lrun[2];
#pragma unroll
  for (int mi = 0; mi < 2; ++mi){
#pragma unroll
    for (int di = 0; di < 4; ++di) oaccT[mi][di] = vzero;
    mrun[mi] = -1e30f; lrun[mi] = 0.f;
  }

  STAGE_T(0, 0);
  __syncthreads();

  for (int t = 0; t < 32; ++t){
    const int cur = t & 1;
    if (t < 31) STAGE_T(cur ^ 1, t + 1);
    const u16* bK = lsK[cur];
    const u16* bV = lsV[cur];

    bf16x8 kf[4][2];
#pragma unroll
    for (int ni = 0; ni < 4; ++ni)
#pragma unroll
      for (int kk = 0; kk < 2; ++kk){
        int row = ni*16 + c15;
        kf[ni][kk] = *reinterpret_cast<const bf16x8*>(bK + row*64 + ((((kk<<2)+g) ^ (row&7)) << 3));
      }
    f32x4 sacc[2][4];
    __builtin_amdgcn_s_setprio(1);
#pragma unroll
    for (int mi = 0; mi < 2; ++mi)
#pragma unroll
      for (int ni = 0; ni < 4; ++ni)
        sacc[mi][ni] = mfma16(kf[ni][1], qf[mi][1], mfma16(kf[ni][0], qf[mi][0], vzero));
    __builtin_amdgcn_s_setprio(0);

    unsigned pk[2][4][2];
#pragma unroll
    for (int mi = 0; mi < 2; ++mi){
      float a0 = fmaxf(fmaxf(sacc[mi][0][0], sacc[mi][0][1]), sacc[mi][0][2]);
      float a1 = fmaxf(fmaxf(sacc[mi][0][3], sacc[mi][1][0]), sacc[mi][1][1]);
      float a2 = fmaxf(fmaxf(sacc[mi][1][2], sacc[mi][1][3]), sacc[mi][2][0]);
      float a3 = fmaxf(fmaxf(sacc[mi][2][1], sacc[mi][2][2]), sacc[mi][2][3]);
      float a4 = fmaxf(fmaxf(sacc[mi][3][0], sacc[mi][3][1]), sacc[mi][3][2]);
      float b0 = fmaxf(fmaxf(a0, a1), a2);
      float b1 = fmaxf(fmaxf(a3, a4), sacc[mi][3][3]);
      float mt = fmaxf(b0, b1);
      mt = fmaxf(mt, __shfl_xor(mt, 16, 64));
      mt = fmaxf(mt, __shfl_xor(mt, 32, 64));
      if (mt > mrun[mi]){
        float f_ = __expf(mrun[mi] - mt);
        mrun[mi] = mt;
        lrun[mi] *= f_;
#pragma unroll
        for (int di = 0; di < 4; ++di) oaccT[mi][di] = oaccT[mi][di] * f_;
      }
      const float mn = mrun[mi];
#pragma unroll
      for (int ni = 0; ni < 4; ++ni){
        float p0 = __expf(sacc[mi][ni][0] - mn);
        float p1 = __expf(sacc[mi][ni][1] - mn);
        float p2 = __expf(sacc[mi][ni][2] - mn);
        float p3 = __expf(sacc[mi][ni][3] - mn);
        pk[mi][ni][0] = pack_trunc(p0, p1);
        pk[mi][ni][1] = pack_trunc(p2, p3);
      }
    }

    bf16x8 pf[2][2];
#pragma unroll
    for (int mi = 0; mi < 2; ++mi)
#pragma unroll
      for (int kk = 0; kk < 2; ++kk){
        union { unsigned u[4]; bf16x8 v; } pu;
#pragma unroll
        for (int w = 0; w < 4; ++w){
          const int p = w & 1;
          const int src = (w < 2) ? srcA : srcB;
          unsigned va = (unsigned)__shfl((int)pk[mi][2*kk    ][p], src, 64);
          unsigned vb = (unsigned)__shfl((int)pk[mi][2*kk + 1][p], src, 64);
          pu.u[w] = hihalf ? vb : va;
        }
        pf[mi][kk] = pu.v;
      }

    bf16x8 vf[4][2];
#pragma unroll
    for (int di = 0; di < 4; ++di)
#pragma unroll
      for (int kk = 0; kk < 2; ++kk){
        int row = di*16 + c15;
        vf[di][kk] = *reinterpret_cast<const bf16x8*>(bV + row*64 + ((((kk<<2)+g) ^ (row&7)) << 3));
      }

    __builtin_amdgcn_s_setprio(1);
#pragma unroll
    for (int mi = 0; mi < 2; ++mi){
      f32x4 ls = mfma16(ones, pf[mi][0], vzero);
      ls = mfma16(ones, pf[mi][1], ls);
      lrun[mi] += ls[0];
    }
#pragma unroll
    for (int mi = 0; mi < 2; ++mi)
#pragma unroll
      for (int di = 0; di < 4; ++di){
        oaccT[mi][di] = mfma16(vf[di][0], pf[mi][0], oaccT[mi][di]);
        oaccT[mi][di] = mfma16(vf[di][1], pf[mi][1], oaccT[mi][di]);
      }
    __builtin_amdgcn_s_setprio(0);

    __syncthreads();
  }

#pragma unroll
  for (int mi = 0; mi < 2; ++mi){
    float inv = 1.f / lrun[mi];
    int q = q0 + mi*16 + c15;
#pragma unroll
    for (int di = 0; di < 4; ++di){
      unsigned lo = pack2(oaccT[mi][di][0] * inv, oaccT[mi][di][1] * inv);
      unsigned hi = pack2(oaccT[mi][di][2] * inv, oaccT[mi][di][3] * inv);
      *reinterpret_cast<uint2*>(O + hb + ((size_t)q << 6) + di*16 + g*4) = make_uint2(lo, hi);
    }
  }
#undef STAGE_T
}

// ---------- launch ----------
extern "C" void kernel_launch(void* const* d_in, const int* in_sizes, int n_in,
                              void* d_out, int out_size, void* d_ws, size_t ws_size,
                              hipStream_t stream){
  const float* x  = (const float*)d_in[0];
  const float* wq = (const float*)d_in[1];
  const float* wk = (const float*)d_in[2];
  const float* wv = (const float*)d_in[3];
  const float* wo = (const float*)d_in[4];
  float* out = (float*)d_out;
  char* ws = (char*)d_ws;
  u16* xb  = (u16*)(ws);                    // 16 MB  x bf16 [8192][1024]
  u16* wqb = (u16*)(ws + (16u << 20));      // 2 MB  } contiguous [3072][1024]
  u16* wkb = (u16*)(ws + (18u << 20));      // 2 MB  }
  u16* wvb = (u16*)(ws + (20u << 20));      // 2 MB  }
  u16* wob = (u16*)(ws + (22u << 20));      // 2 MB
  u16* Qb  = (u16*)(ws + (24u << 20));      // 16 MB [B,H,S,Dk] pre-scaled 1/8
  u16* Kb  = (u16*)(ws + (40u << 20));      // 16 MB [B,H,S,Dk]
  u16* Vtb = (u16*)(ws + (56u << 20));      // 16 MB [B,H,Dk,S]
  u16* Ob  = (u16*)(ws + (72u << 20));      // 16 MB [B,H,S,Dk]

  cvt_kernel<<<8192, 256, 0, stream>>>(x, xb, 2097152);
  cvt4_kernel<<<4096, 256, 0, stream>>>(wq, wk, wv, wo, wqb, wkb, wvb, wob);
  gemm_qkv<<<dim3(64, 24), 256, 0, stream>>>(xb, wqb, Qb, Kb, Vtb);
  attn_kernel<<<1024, 256, 0, stream>>>(Qb, Kb, Vtb, Ob);
  gemm_out<<<dim3(64, 8), 256, 0, stream>>>(Ob, wob, out);
}

// Round 14
// 184.336 us; speedup vs baseline: 1.8581x; 1.1042x over previous
//
#include <hip/hip_runtime.h>
#include <hip/hip_bf16.h>

typedef unsigned short u16;
typedef __bf16 bf16x8 __attribute__((ext_vector_type(8)));
typedef float f32x4 __attribute__((ext_vector_type(4)));

#define DEV static __device__ __forceinline__

// ---------- helpers ----------
DEV u16 f2b(float f){                       // fp32 -> bf16 (RNE)
  union { float f; unsigned u; } v; v.f = f;
  unsigned r = (v.u + 0x7FFFu + ((v.u >> 16) & 1u)) >> 16;
  return (u16)r;
}

DEV unsigned pack2(float lo, float hi){     // 2 f32 -> packed bf16x2 (RNE), lo in [15:0]
  __hip_bfloat162 h = __float22bfloat162_rn(float2{lo, hi});
  union { __hip_bfloat162 h; unsigned u; } c; c.h = h;
  return c.u;
}

DEV unsigned pack_trunc(float lo, float hi){ // 2 f32 -> packed bf16x2 (truncate): 1 v_perm_b32
  union { float f; unsigned u; } a, b; a.f = lo; b.f = hi;
  return __builtin_amdgcn_perm(b.u, a.u, 0x07060302u);
}

DEV void gload16(const void* g, void* l){   // async global->LDS, 16B/lane
  __builtin_amdgcn_global_load_lds((const __attribute__((address_space(1))) void*)g,
                                   (__attribute__((address_space(3))) void*)l, 16, 0, 0);
}

DEV f32x4 mfma16(bf16x8 a, bf16x8 b, f32x4 c){
  return __builtin_amdgcn_mfma_f32_16x16x32_bf16(a, b, c, 0, 0, 0);
}

// ---------- fp32 -> bf16 convert (x) ----------
__global__ void cvt_kernel(const float* __restrict__ src, u16* __restrict__ dst, int n4){
  int i = blockIdx.x * 256 + threadIdx.x;
  if (i < n4){
    float4 v = reinterpret_cast<const float4*>(src)[i];
    ushort4 o;
    o.x = f2b(v.x); o.y = f2b(v.y); o.z = f2b(v.z); o.w = f2b(v.w);
    reinterpret_cast<ushort4*>(dst)[i] = o;
  }
}

// ---------- fp32 -> bf16 convert (4 weights, one dispatch) ----------
__global__ void cvt4_kernel(const float* __restrict__ w0, const float* __restrict__ w1,
                            const float* __restrict__ w2, const float* __restrict__ w3,
                            u16* __restrict__ o0, u16* __restrict__ o1,
                            u16* __restrict__ o2, u16* __restrict__ o3){
  int r = blockIdx.x >> 10;
  int i = (blockIdx.x & 1023) * 256 + threadIdx.x;
  const float* s = (r == 0) ? w0 : (r == 1) ? w1 : (r == 2) ? w2 : w3;
  u16*         d = (r == 0) ? o0 : (r == 1) ? o1 : (r == 2) ? o2 : o3;
  float4 v = reinterpret_cast<const float4*>(s)[i];
  ushort4 o;
  o.x = f2b(v.x); o.y = f2b(v.y); o.z = f2b(v.z); o.w = f2b(v.w);
  reinterpret_cast<ushort4*>(d)[i] = o;
}

// ---------- fused QKV GEMM: C[m,n] = sum_k x[m,k]*Wqkv[n,k], M=8192 N=3072 K=1024 ----------
// V epilogue stores kv PI-PERMUTED within each 64-tile:
//   slot = (kv&0x20) | ((kv&0x0C)<<1) | ((kv&0x10)>>2) | (kv&3)
// so attention's PV B-operand is the raw S^T register layout (zero shuffles).
__global__ __launch_bounds__(256, 2)
void gemm_qkv(const u16* __restrict__ A, const u16* __restrict__ B,
              u16* __restrict__ Qb, u16* __restrict__ Kb, u16* __restrict__ Vtb){
  __shared__ __align__(16) u16 lsA[128*64];
  __shared__ __align__(16) u16 lsB[128*64];
  const int tid  = threadIdx.x;
  const int lane = tid & 63, wid = tid >> 6;
  const int g = lane >> 4, c15 = lane & 15;
  const int m0 = blockIdx.x * 128, n0 = blockIdx.y * 128;
  const int wm = (wid >> 1) * 64, wn = (wid & 1) * 64;
  const f32x4 vzero = {0.f, 0.f, 0.f, 0.f};

  f32x4 acc[4][4];
#pragma unroll
  for (int mi = 0; mi < 4; ++mi)
#pragma unroll
    for (int ni = 0; ni < 4; ++ni) acc[mi][ni] = vzero;

  for (int kt = 0; kt < 16; ++kt){
    __syncthreads();
#pragma unroll
    for (int i = 0; i < 4; ++i){
      int c = i * 256 + tid;
      int row = c >> 3, gc = (c & 7) ^ (row & 7);
      gload16(A + ((size_t)(m0 + row) << 10) + (kt << 6) + (gc << 3), lsA + (size_t)c * 8);
    }
#pragma unroll
    for (int i = 0; i < 4; ++i){
      int c = i * 256 + tid;
      int row = c >> 3, gc = (c & 7) ^ (row & 7);
      gload16(B + ((size_t)(n0 + row) << 10) + (kt << 6) + (gc << 3), lsB + (size_t)c * 8);
    }
    __syncthreads();

    bf16x8 af[4][2], bf[4][2];
#pragma unroll
    for (int mi = 0; mi < 4; ++mi)
#pragma unroll
      for (int kk = 0; kk < 2; ++kk){
        int ra = wm + mi * 16 + c15;
        af[mi][kk] = *reinterpret_cast<const bf16x8*>(lsA + ra * 64 + ((((kk << 2) + g) ^ (ra & 7)) << 3));
        int rb = wn + mi * 16 + c15;
        bf[mi][kk] = *reinterpret_cast<const bf16x8*>(lsB + rb * 64 + ((((kk << 2) + g) ^ (rb & 7)) << 3));
      }
#pragma unroll
    for (int mi = 0; mi < 4; ++mi)
#pragma unroll
      for (int ni = 0; ni < 4; ++ni){
        acc[mi][ni] = mfma16(af[mi][0], bf[ni][0], acc[mi][ni]);
        acc[mi][ni] = mfma16(af[mi][1], bf[ni][1], acc[mi][ni]);
      }
  }

  const int reg = n0 >> 10;                   // 0:Q 1:K 2:V (wave-uniform)
#pragma unroll
  for (int mi = 0; mi < 4; ++mi)
#pragma unroll
    for (int ni = 0; ni < 4; ++ni){
      int mrow = m0 + wm + mi * 16 + g * 4;
      int ncolL = (n0 + wn + ni * 16 + c15) & 1023;
      int b = mrow >> 11, s = mrow & 2047;
      int h = ncolL >> 6, dk = ncolL & 63;
      if (reg < 2){
        const float sc = (reg == 0) ? 0.125f : 1.0f;
        u16* dst = (reg == 0 ? Qb : Kb) + (((size_t)(b * 16 + h) * 2048 + s) << 6) + dk;
#pragma unroll
        for (int r = 0; r < 4; ++r) dst[(size_t)r << 6] = f2b(acc[mi][ni][r] * sc);
      } else {
        ushort4 o;
        o.x = f2b(acc[mi][ni][0]); o.y = f2b(acc[mi][ni][1]);
        o.z = f2b(acc[mi][ni][2]); o.w = f2b(acc[mi][ni][3]);
        int sl = s & 63;                       // pi-permute within 64-tile (4-block aligned)
        int np = (sl & 0x20) | ((sl & 0x0C) << 1) | ((sl & 0x10) >> 2);
        *reinterpret_cast<ushort4*>(Vtb + (((size_t)(b * 16 + h) * 64 + dk) << 11) + (s & ~63) + np) = o;
      }
    }
}

// ---------- O-projection GEMM: out[m,n] = sum_k O[m,k]*Wo[n,k] (fp32 out) ----------
__global__ __launch_bounds__(256, 2)
void gemm_out(const u16* __restrict__ A, const u16* __restrict__ B, float* __restrict__ Out){
  __shared__ __align__(16) u16 lsA[128*64];
  __shared__ __align__(16) u16 lsB[128*64];
  const int tid  = threadIdx.x;
  const int lane = tid & 63, wid = tid >> 6;
  const int g = lane >> 4, c15 = lane & 15;
  const int m0 = blockIdx.x * 128, n0 = blockIdx.y * 128;
  const int wm = (wid >> 1) * 64, wn = (wid & 1) * 64;
  const f32x4 vzero = {0.f, 0.f, 0.f, 0.f};

  f32x4 acc[4][4];
#pragma unroll
  for (int mi = 0; mi < 4; ++mi)
#pragma unroll
    for (int ni = 0; ni < 4; ++ni) acc[mi][ni] = vzero;

  for (int kt = 0; kt < 16; ++kt){
    __syncthreads();
#pragma unroll
    for (int i = 0; i < 4; ++i){              // A from [B,H,S,Dk]-layout O buffer; kt == head
      int c = i * 256 + tid;
      int row = c >> 3, gc = (c & 7) ^ (row & 7);
      int b = m0 >> 11, s = (m0 & 2047) + row;
      gload16(A + (((size_t)(b * 16 + kt) * 2048 + s) << 6) + (gc << 3), lsA + (size_t)c * 8);
    }
#pragma unroll
    for (int i = 0; i < 4; ++i){
      int c = i * 256 + tid;
      int row = c >> 3, gc = (c & 7) ^ (row & 7);
      gload16(B + ((size_t)(n0 + row) << 10) + (kt << 6) + (gc << 3), lsB + (size_t)c * 8);
    }
    __syncthreads();

    bf16x8 af[4][2], bf[4][2];
#pragma unroll
    for (int mi = 0; mi < 4; ++mi)
#pragma unroll
      for (int kk = 0; kk < 2; ++kk){
        int ra = wm + mi * 16 + c15;
        af[mi][kk] = *reinterpret_cast<const bf16x8*>(lsA + ra * 64 + ((((kk << 2) + g) ^ (ra & 7)) << 3));
        int rb = wn + mi * 16 + c15;
        bf[mi][kk] = *reinterpret_cast<const bf16x8*>(lsB + rb * 64 + ((((kk << 2) + g) ^ (rb & 7)) << 3));
      }
#pragma unroll
    for (int mi = 0; mi < 4; ++mi)
#pragma unroll
      for (int ni = 0; ni < 4; ++ni){
        acc[mi][ni] = mfma16(af[mi][0], bf[ni][0], acc[mi][ni]);
        acc[mi][ni] = mfma16(af[mi][1], bf[ni][1], acc[mi][ni]);
      }
  }

#pragma unroll
  for (int mi = 0; mi < 4; ++mi)
#pragma unroll
    for (int ni = 0; ni < 4; ++ni){
      int mrow = m0 + wm + mi * 16 + g * 4;
      int ncol = n0 + wn + ni * 16 + c15;
      float* dst = Out + (size_t)mrow * 1024 + ncol;
#pragma unroll
      for (int r = 0; r < 4; ++r) dst[(size_t)r << 10] = acc[mi][ni][r];
    }
}

// ---------- flash attention v14: shuffle-free PV via pi-permuted V ----------
// S^T = mfma(K, Q): lane (g,q) reg (4ni..): S[q][kv=16ni+4g+r].
// PV k-map chosen as pi(g,e,kk) = 32kk + 16*(e>>2) + 4g + (e&3):
//   B-operand pf[mi][kk] = {pk[2kk][0], pk[2kk][1], pk[2kk+1][0], pk[2kk+1][1]}  (pure concat)
//   A-operand (V^T) holds kv pi-permuted -- pre-permuted in GLOBAL by gemm_qkv, so
//   staging + vf ds_read code are byte-identical to the proven version.
__global__ __launch_bounds__(256, 4)
void attn_kernel(const u16* __restrict__ Q, const u16* __restrict__ K,
                 const u16* __restrict__ Vt, u16* __restrict__ O){
  __shared__ __align__(16) u16 lsK[2][64*64];
  __shared__ __align__(16) u16 lsV[2][64*64];
  const int tid  = threadIdx.x;
  const int lane = tid & 63;
  const int g = lane >> 4, c15 = lane & 15;
  const int bid  = blockIdx.x;
  const int head = (bid & 7) * 8 + ((bid >> 3) >> 4);   // XCD-grouped head
  const int qt   = (bid >> 3) & 15;
  const size_t hb = (size_t)head << 17;
  const int q0 = qt * 128 + (tid >> 6) * 32;
  const f32x4 vzero = {0.f, 0.f, 0.f, 0.f};

#define STAGE_T(tb, tt) do {                                                        \
    _Pragma("unroll")                                                               \
    for (int i_ = 0; i_ < 2; ++i_){                                                 \
      int c_ = i_ * 256 + tid;                                                      \
      int row_ = c_ >> 3, gc_ = (c_ & 7) ^ (row_ & 7);                              \
      gload16(K  + hb + ((size_t)((tt)*64 + row_) << 6) + (gc_ << 3), lsK[tb] + (size_t)c_ * 8); \
      gload16(Vt + hb + ((size_t)row_ << 11) + (tt)*64 + (gc_ << 3),  lsV[tb] + (size_t)c_ * 8); \
    }                                                                               \
  } while (0)

  bf16x8 qf[2][2];
#pragma unroll
  for (int mi = 0; mi < 2; ++mi)
#pragma unroll
    for (int kk = 0; kk < 2; ++kk)
      qf[mi][kk] = *reinterpret_cast<const bf16x8*>(Q + hb + ((size_t)(q0 + mi*16 + c15) << 6) + kk*32 + g*8);

  union { unsigned u[4]; bf16x8 v; } ou;        // all-ones bf16 A-frag for row sums
  ou.u[0] = ou.u[1] = ou.u[2] = ou.u[3] = 0x3F803F80u;
  const bf16x8 ones = ou.v;

  f32x4 oaccT[2][4];
  float mrun[2], lrun[2];
#pragma unroll
  for (int mi = 0; mi < 2; ++mi){
#pragma unroll
    for (int di = 0; di < 4; ++di) oaccT[mi][di] = vzero;
    mrun[mi] = -1e30f; lrun[mi] = 0.f;
  }

  STAGE_T(0, 0);
  __syncthreads();

  for (int t = 0; t < 32; ++t){
    const int cur = t & 1;
    if (t < 31) STAGE_T(cur ^ 1, t + 1);        // prefetch next tile; end-of-iter barrier drains
    const u16* bK = lsK[cur];
    const u16* bV = lsV[cur];

    bf16x8 kf[4][2];                            // K frags (A operand: row = kv)
#pragma unroll
    for (int ni = 0; ni < 4; ++ni)
#pragma unroll
      for (int kk = 0; kk < 2; ++kk){
        int row = ni*16 + c15;
        kf[ni][kk] = *reinterpret_cast<const bf16x8*>(bK + row*64 + ((((kk<<2)+g) ^ (row&7)) << 3));
      }
    f32x4 sacc[2][4];                           // S^T: lane c15=q, reg g*4+r = kv
    __builtin_amdgcn_s_setprio(1);
#pragma unroll
    for (int mi = 0; mi < 2; ++mi)
#pragma unroll
      for (int ni = 0; ni < 4; ++ni)
        sacc[mi][ni] = mfma16(kf[ni][1], qf[mi][1], mfma16(kf[ni][0], qf[mi][0], vzero));
    __builtin_amdgcn_s_setprio(0);

    // lane-local online softmax -> packed P, already in PV B-operand layout (zero shuffles)
    bf16x8 pf[2][2];
#pragma unroll
    for (int mi = 0; mi < 2; ++mi){
      float a0 = fmaxf(fmaxf(sacc[mi][0][0], sacc[mi][0][1]), sacc[mi][0][2]);
      float a1 = fmaxf(fmaxf(sacc[mi][0][3], sacc[mi][1][0]), sacc[mi][1][1]);
      float a2 = fmaxf(fmaxf(sacc[mi][1][2], sacc[mi][1][3]), sacc[mi][2][0]);
      float a3 = fmaxf(fmaxf(sacc[mi][2][1], sacc[mi][2][2]), sacc[mi][2][3]);
      float a4 = fmaxf(fmaxf(sacc[mi][3][0], sacc[mi][3][1]), sacc[mi][3][2]);
      float b0 = fmaxf(fmaxf(a0, a1), a2);
      float b1 = fmaxf(fmaxf(a3, a4), sacc[mi][3][3]);
      float mt = fmaxf(b0, b1);
      mt = fmaxf(mt, __shfl_xor(mt, 16, 64));
      mt = fmaxf(mt, __shfl_xor(mt, 32, 64));
      if (mt > mrun[mi]){                       // exact defer: skip rescale when no growth
        float f_ = __expf(mrun[mi] - mt);
        mrun[mi] = mt;
        lrun[mi] *= f_;
#pragma unroll
        for (int di = 0; di < 4; ++di) oaccT[mi][di] = oaccT[mi][di] * f_;
      }
      const float mn = mrun[mi];
#pragma unroll
      for (int kk = 0; kk < 2; ++kk){
        union { unsigned u[4]; bf16x8 v; } pu;
#pragma unroll
        for (int h2 = 0; h2 < 2; ++h2){         // ni = 2kk + h2
          const int ni = 2*kk + h2;
          float p0 = __expf(sacc[mi][ni][0] - mn);
          float p1 = __expf(sacc[mi][ni][1] - mn);
          float p2 = __expf(sacc[mi][ni][2] - mn);
          float p3 = __expf(sacc[mi][ni][3] - mn);
          pu.u[2*h2    ] = pack_trunc(p0, p1);
          pu.u[2*h2 + 1] = pack_trunc(p2, p3);
        }
        pf[mi][kk] = pu.v;
      }
    }

    bf16x8 vf[4][2];                            // V^T frags (pi-permuted data, same addresses)
#pragma unroll
    for (int di = 0; di < 4; ++di)
#pragma unroll
      for (int kk = 0; kk < 2; ++kk){
        int row = di*16 + c15;
        vf[di][kk] = *reinterpret_cast<const bf16x8*>(bV + row*64 + ((((kk<<2)+g) ^ (row&7)) << 3));
      }

    // row sums + PV on the MFMA pipe (ones-sum is permutation-invariant)
    __builtin_amdgcn_s_setprio(1);
#pragma unroll
    for (int mi = 0; mi < 2; ++mi){
      f32x4 ls = mfma16(ones, pf[mi][0], vzero);
      ls = mfma16(ones, pf[mi][1], ls);
      lrun[mi] += ls[0];
    }
#pragma unroll
    for (int mi = 0; mi < 2; ++mi)
#pragma unroll
      for (int di = 0; di < 4; ++di){
        oaccT[mi][di] = mfma16(vf[di][0], pf[mi][0], oaccT[mi][di]);
        oaccT[mi][di] = mfma16(vf[di][1], pf[mi][1], oaccT[mi][di]);
      }
    __builtin_amdgcn_s_setprio(0);

    __syncthreads();                            // drains prefetch vmcnt + protects buffer swap
  }

  // normalize + write O [B,H,S,Dk]; lane c15=q, dk = di*16+g*4+r (RNE pack)
#pragma unroll
  for (int mi = 0; mi < 2; ++mi){
    float inv = 1.f / lrun[mi];
    int q = q0 + mi*16 + c15;
#pragma unroll
    for (int di = 0; di < 4; ++di){
      unsigned lo = pack2(oaccT[mi][di][0] * inv, oaccT[mi][di][1] * inv);
      unsigned hi = pack2(oaccT[mi][di][2] * inv, oaccT[mi][di][3] * inv);
      *reinterpret_cast<uint2*>(O + hb + ((size_t)q << 6) + di*16 + g*4) = make_uint2(lo, hi);
    }
  }
#undef STAGE_T
}

// ---------- launch ----------
extern "C" void kernel_launch(void* const* d_in, const int* in_sizes, int n_in,
                              void* d_out, int out_size, void* d_ws, size_t ws_size,
                              hipStream_t stream){
  const float* x  = (const float*)d_in[0];
  const float* wq = (const float*)d_in[1];
  const float* wk = (const float*)d_in[2];
  const float* wv = (const float*)d_in[3];
  const float* wo = (const float*)d_in[4];
  float* out = (float*)d_out;
  char* ws = (char*)d_ws;
  u16* xb  = (u16*)(ws);                    // 16 MB  x bf16 [8192][1024]
  u16* wqb = (u16*)(ws + (16u << 20));      // 2 MB  } contiguous [3072][1024]
  u16* wkb = (u16*)(ws + (18u << 20));      // 2 MB  }
  u16* wvb = (u16*)(ws + (20u << 20));      // 2 MB  }
  u16* wob = (u16*)(ws + (22u << 20));      // 2 MB
  u16* Qb  = (u16*)(ws + (24u << 20));      // 16 MB [B,H,S,Dk] pre-scaled 1/8
  u16* Kb  = (u16*)(ws + (40u << 20));      // 16 MB [B,H,S,Dk]
  u16* Vtb = (u16*)(ws + (56u << 20));      // 16 MB [B,H,Dk,S] pi-permuted per 64-tile
  u16* Ob  = (u16*)(ws + (72u << 20));      // 16 MB [B,H,S,Dk]

  cvt_kernel<<<8192, 256, 0, stream>>>(x, xb, 2097152);
  cvt4_kernel<<<4096, 256, 0, stream>>>(wq, wk, wv, wo, wqb, wkb, wvb, wob);
  gemm_qkv<<<dim3(64, 24), 256, 0, stream>>>(xb, wqb, Qb, Kb, Vtb);
  attn_kernel<<<1024, 256, 0, stream>>>(Qb, Kb, Vtb, Ob);
  gemm_out<<<dim3(64, 8), 256, 0, stream>>>(Ob, wob, out);
}

// Round 15
// 177.551 us; speedup vs baseline: 1.9291x; 1.0382x over previous
//
#include <hip/hip_runtime.h>
#include <hip/hip_bf16.h>

typedef unsigned short u16;
typedef __bf16 bf16x8 __attribute__((ext_vector_type(8)));
typedef float f32x4 __attribute__((ext_vector_type(4)));

#define DEV static __device__ __forceinline__

// ---------- helpers ----------
DEV u16 f2b(float f){                       // fp32 -> bf16 (RNE)
  union { float f; unsigned u; } v; v.f = f;
  unsigned r = (v.u + 0x7FFFu + ((v.u >> 16) & 1u)) >> 16;
  return (u16)r;
}

DEV unsigned pack2(float lo, float hi){     // 2 f32 -> packed bf16x2 (RNE), lo in [15:0]
  __hip_bfloat162 h = __float22bfloat162_rn(float2{lo, hi});
  union { __hip_bfloat162 h; unsigned u; } c; c.h = h;
  return c.u;
}

DEV unsigned pack_trunc(float lo, float hi){ // 2 f32 -> packed bf16x2 (truncate): 1 v_perm_b32
  union { float f; unsigned u; } a, b; a.f = lo; b.f = hi;
  return __builtin_amdgcn_perm(b.u, a.u, 0x07060302u);
}

DEV void gload16(const void* g, void* l){   // async global->LDS, 16B/lane
  __builtin_amdgcn_global_load_lds((const __attribute__((address_space(1))) void*)g,
                                   (__attribute__((address_space(3))) void*)l, 16, 0, 0);
}

DEV f32x4 mfma16(bf16x8 a, bf16x8 b, f32x4 c){
  return __builtin_amdgcn_mfma_f32_16x16x32_bf16(a, b, c, 0, 0, 0);
}

// ---------- fp32 -> bf16 convert (x + 4 weights, single dispatch) ----------
__global__ void cvt_all(const float* __restrict__ x,
                        const float* __restrict__ w0, const float* __restrict__ w1,
                        const float* __restrict__ w2, const float* __restrict__ w3,
                        u16* __restrict__ xb,
                        u16* __restrict__ o0, u16* __restrict__ o1,
                        u16* __restrict__ o2, u16* __restrict__ o3){
  const int bid = blockIdx.x;
  const float* s; u16* d; int i;
  if (bid < 8192){                           // x: 8192 blocks x 256 float4s
    s = x; d = xb; i = bid * 256 + threadIdx.x;
  } else {                                   // weights: 4 x 1024 blocks
    int r = (bid - 8192) >> 10;
    i = ((bid - 8192) & 1023) * 256 + threadIdx.x;
    s = (r == 0) ? w0 : (r == 1) ? w1 : (r == 2) ? w2 : w3;
    d = (r == 0) ? o0 : (r == 1) ? o1 : (r == 2) ? o2 : o3;
  }
  float4 v = reinterpret_cast<const float4*>(s)[i];
  ushort4 o;
  o.x = f2b(v.x); o.y = f2b(v.y); o.z = f2b(v.z); o.w = f2b(v.w);
  reinterpret_cast<ushort4*>(d)[i] = o;
}

// ---------- fused QKV GEMM: C[m,n] = sum_k x[m,k]*Wqkv[n,k], M=8192 N=3072 K=1024 ----------
// V epilogue stores kv PI-PERMUTED within each 64-tile:
//   slot = (kv&0x20) | ((kv&0x0C)<<1) | ((kv&0x10)>>2) | (kv&3)
// so attention's PV B-operand is the raw S^T register layout (zero shuffles).
__global__ __launch_bounds__(256, 2)
void gemm_qkv(const u16* __restrict__ A, const u16* __restrict__ B,
              u16* __restrict__ Qb, u16* __restrict__ Kb, u16* __restrict__ Vtb){
  __shared__ __align__(16) u16 lsA[128*64];
  __shared__ __align__(16) u16 lsB[128*64];
  const int tid  = threadIdx.x;
  const int lane = tid & 63, wid = tid >> 6;
  const int g = lane >> 4, c15 = lane & 15;
  const int m0 = blockIdx.x * 128, n0 = blockIdx.y * 128;
  const int wm = (wid >> 1) * 64, wn = (wid & 1) * 64;
  const f32x4 vzero = {0.f, 0.f, 0.f, 0.f};

  f32x4 acc[4][4];
#pragma unroll
  for (int mi = 0; mi < 4; ++mi)
#pragma unroll
    for (int ni = 0; ni < 4; ++ni) acc[mi][ni] = vzero;

  for (int kt = 0; kt < 16; ++kt){
    __syncthreads();
#pragma unroll
    for (int i = 0; i < 4; ++i){
      int c = i * 256 + tid;
      int row = c >> 3, gc = (c & 7) ^ (row & 7);
      gload16(A + ((size_t)(m0 + row) << 10) + (kt << 6) + (gc << 3), lsA + (size_t)c * 8);
    }
#pragma unroll
    for (int i = 0; i < 4; ++i){
      int c = i * 256 + tid;
      int row = c >> 3, gc = (c & 7) ^ (row & 7);
      gload16(B + ((size_t)(n0 + row) << 10) + (kt << 6) + (gc << 3), lsB + (size_t)c * 8);
    }
    __syncthreads();

    bf16x8 af[4][2], bf[4][2];
#pragma unroll
    for (int mi = 0; mi < 4; ++mi)
#pragma unroll
      for (int kk = 0; kk < 2; ++kk){
        int ra = wm + mi * 16 + c15;
        af[mi][kk] = *reinterpret_cast<const bf16x8*>(lsA + ra * 64 + ((((kk << 2) + g) ^ (ra & 7)) << 3));
        int rb = wn + mi * 16 + c15;
        bf[mi][kk] = *reinterpret_cast<const bf16x8*>(lsB + rb * 64 + ((((kk << 2) + g) ^ (rb & 7)) << 3));
      }
#pragma unroll
    for (int mi = 0; mi < 4; ++mi)
#pragma unroll
      for (int ni = 0; ni < 4; ++ni){
        acc[mi][ni] = mfma16(af[mi][0], bf[ni][0], acc[mi][ni]);
        acc[mi][ni] = mfma16(af[mi][1], bf[ni][1], acc[mi][ni]);
      }
  }

  const int reg = n0 >> 10;                   // 0:Q 1:K 2:V (wave-uniform)
#pragma unroll
  for (int mi = 0; mi < 4; ++mi)
#pragma unroll
    for (int ni = 0; ni < 4; ++ni){
      int mrow = m0 + wm + mi * 16 + g * 4;
      int ncolL = (n0 + wn + ni * 16 + c15) & 1023;
      int b = mrow >> 11, s = mrow & 2047;
      int h = ncolL >> 6, dk = ncolL & 63;
      if (reg < 2){
        // Q scale = (1/8) * log2(e): scores live in exp2 domain
        const float sc = (reg == 0) ? 0.18033688011112042f : 1.0f;
        u16* dst = (reg == 0 ? Qb : Kb) + (((size_t)(b * 16 + h) * 2048 + s) << 6) + dk;
#pragma unroll
        for (int r = 0; r < 4; ++r) dst[(size_t)r << 6] = f2b(acc[mi][ni][r] * sc);
      } else {
        ushort4 o;
        o.x = f2b(acc[mi][ni][0]); o.y = f2b(acc[mi][ni][1]);
        o.z = f2b(acc[mi][ni][2]); o.w = f2b(acc[mi][ni][3]);
        int sl = s & 63;                       // pi-permute within 64-tile (4-block aligned)
        int np = (sl & 0x20) | ((sl & 0x0C) << 1) | ((sl & 0x10) >> 2);
        *reinterpret_cast<ushort4*>(Vtb + (((size_t)(b * 16 + h) * 64 + dk) << 11) + (s & ~63) + np) = o;
      }
    }
}

// ---------- O-projection GEMM: out[m,n] = sum_k O[m,k]*Wo[n,k] (fp32 out) ----------
__global__ __launch_bounds__(256, 2)
void gemm_out(const u16* __restrict__ A, const u16* __restrict__ B, float* __restrict__ Out){
  __shared__ __align__(16) u16 lsA[128*64];
  __shared__ __align__(16) u16 lsB[128*64];
  const int tid  = threadIdx.x;
  const int lane = tid & 63, wid = tid >> 6;
  const int g = lane >> 4, c15 = lane & 15;
  const int m0 = blockIdx.x * 128, n0 = blockIdx.y * 128;
  const int wm = (wid >> 1) * 64, wn = (wid & 1) * 64;
  const f32x4 vzero = {0.f, 0.f, 0.f, 0.f};

  f32x4 acc[4][4];
#pragma unroll
  for (int mi = 0; mi < 4; ++mi)
#pragma unroll
    for (int ni = 0; ni < 4; ++ni) acc[mi][ni] = vzero;

  for (int kt = 0; kt < 16; ++kt){
    __syncthreads();
#pragma unroll
    for (int i = 0; i < 4; ++i){              // A from [B,H,S,Dk]-layout O buffer; kt == head
      int c = i * 256 + tid;
      int row = c >> 3, gc = (c & 7) ^ (row & 7);
      int b = m0 >> 11, s = (m0 & 2047) + row;
      gload16(A + (((size_t)(b * 16 + kt) * 2048 + s) << 6) + (gc << 3), lsA + (size_t)c * 8);
    }
#pragma unroll
    for (int i = 0; i < 4; ++i){
      int c = i * 256 + tid;
      int row = c >> 3, gc = (c & 7) ^ (row & 7);
      gload16(B + ((size_t)(n0 + row) << 10) + (kt << 6) + (gc << 3), lsB + (size_t)c * 8);
    }
    __syncthreads();

    bf16x8 af[4][2], bf[4][2];
#pragma unroll
    for (int mi = 0; mi < 4; ++mi)
#pragma unroll
      for (int kk = 0; kk < 2; ++kk){
        int ra = wm + mi * 16 + c15;
        af[mi][kk] = *reinterpret_cast<const bf16x8*>(lsA + ra * 64 + ((((kk << 2) + g) ^ (ra & 7)) << 3));
        int rb = wn + mi * 16 + c15;
        bf[mi][kk] = *reinterpret_cast<const bf16x8*>(lsB + rb * 64 + ((((kk << 2) + g) ^ (rb & 7)) << 3));
      }
#pragma unroll
    for (int mi = 0; mi < 4; ++mi)
#pragma unroll
      for (int ni = 0; ni < 4; ++ni){
        acc[mi][ni] = mfma16(af[mi][0], bf[ni][0], acc[mi][ni]);
        acc[mi][ni] = mfma16(af[mi][1], bf[ni][1], acc[mi][ni]);
      }
  }

#pragma unroll
  for (int mi = 0; mi < 4; ++mi)
#pragma unroll
    for (int ni = 0; ni < 4; ++ni){
      int mrow = m0 + wm + mi * 16 + g * 4;
      int ncol = n0 + wn + ni * 16 + c15;
      float* dst = Out + (size_t)mrow * 1024 + ncol;
#pragma unroll
      for (int r = 0; r < 4; ++r) dst[(size_t)r << 10] = acc[mi][ni][r];
    }
}

// ---------- flash attention v15: shuffle-free PV + exp2-domain softmax ----------
// Q pre-scaled 0.125*log2(e) -> scores in log2 units; exp via raw v_exp_f32 (2^x).
// S^T = mfma(K, Q): lane (g,q) reg: S[q][kv=16ni+4g+r].
// PV k-map pi(g,e,kk) = 32kk + 16*(e>>2) + 4g + (e&3): B-operand = register concat of
// packed P; V^T holds kv pi-permuted (pre-permuted in GLOBAL by gemm_qkv).
__global__ __launch_bounds__(256, 4)
void attn_kernel(const u16* __restrict__ Q, const u16* __restrict__ K,
                 const u16* __restrict__ Vt, u16* __restrict__ O){
  __shared__ __align__(16) u16 lsK[2][64*64];
  __shared__ __align__(16) u16 lsV[2][64*64];
  const int tid  = threadIdx.x;
  const int lane = tid & 63;
  const int g = lane >> 4, c15 = lane & 15;
  const int bid  = blockIdx.x;
  const int head = (bid & 7) * 8 + ((bid >> 3) >> 4);   // XCD-grouped head
  const int qt   = (bid >> 3) & 15;
  const size_t hb = (size_t)head << 17;
  const int q0 = qt * 128 + (tid >> 6) * 32;
  const f32x4 vzero = {0.f, 0.f, 0.f, 0.f};

#define STAGE_T(tb, tt) do {                                                        \
    _Pragma("unroll")                                                               \
    for (int i_ = 0; i_ < 2; ++i_){                                                 \
      int c_ = i_ * 256 + tid;                                                      \
      int row_ = c_ >> 3, gc_ = (c_ & 7) ^ (row_ & 7);                              \
      gload16(K  + hb + ((size_t)((tt)*64 + row_) << 6) + (gc_ << 3), lsK[tb] + (size_t)c_ * 8); \
      gload16(Vt + hb + ((size_t)row_ << 11) + (tt)*64 + (gc_ << 3),  lsV[tb] + (size_t)c_ * 8); \
    }                                                                               \
  } while (0)

  bf16x8 qf[2][2];
#pragma unroll
  for (int mi = 0; mi < 2; ++mi)
#pragma unroll
    for (int kk = 0; kk < 2; ++kk)
      qf[mi][kk] = *reinterpret_cast<const bf16x8*>(Q + hb + ((size_t)(q0 + mi*16 + c15) << 6) + kk*32 + g*8);

  union { unsigned u[4]; bf16x8 v; } ou;        // all-ones bf16 A-frag for row sums
  ou.u[0] = ou.u[1] = ou.u[2] = ou.u[3] = 0x3F803F80u;
  const bf16x8 ones = ou.v;

  f32x4 oaccT[2][4];
  float mrun[2], lrun[2];
#pragma unroll
  for (int mi = 0; mi < 2; ++mi){
#pragma unroll
    for (int di = 0; di < 4; ++di) oaccT[mi][di] = vzero;
    mrun[mi] = -1e30f; lrun[mi] = 0.f;
  }

  STAGE_T(0, 0);
  __syncthreads();

  for (int t = 0; t < 32; ++t){
    const int cur = t & 1;
    if (t < 31) STAGE_T(cur ^ 1, t + 1);        // prefetch next tile; end-of-iter barrier drains
    const u16* bK = lsK[cur];
    const u16* bV = lsV[cur];

    bf16x8 kf[4][2];                            // K frags (A operand: row = kv)
#pragma unroll
    for (int ni = 0; ni < 4; ++ni)
#pragma unroll
      for (int kk = 0; kk < 2; ++kk){
        int row = ni*16 + c15;
        kf[ni][kk] = *reinterpret_cast<const bf16x8*>(bK + row*64 + ((((kk<<2)+g) ^ (row&7)) << 3));
      }
    f32x4 sacc[2][4];                           // S^T: lane c15=q, reg g*4+r = kv (log2 units)
    __builtin_amdgcn_s_setprio(1);
#pragma unroll
    for (int mi = 0; mi < 2; ++mi)
#pragma unroll
      for (int ni = 0; ni < 4; ++ni)
        sacc[mi][ni] = mfma16(kf[ni][1], qf[mi][1], mfma16(kf[ni][0], qf[mi][0], vzero));
    __builtin_amdgcn_s_setprio(0);

    // lane-local online softmax (exp2 domain) -> packed P in PV B-operand layout
    bf16x8 pf[2][2];
#pragma unroll
    for (int mi = 0; mi < 2; ++mi){
      float a0 = fmaxf(fmaxf(sacc[mi][0][0], sacc[mi][0][1]), sacc[mi][0][2]);
      float a1 = fmaxf(fmaxf(sacc[mi][0][3], sacc[mi][1][0]), sacc[mi][1][1]);
      float a2 = fmaxf(fmaxf(sacc[mi][1][2], sacc[mi][1][3]), sacc[mi][2][0]);
      float a3 = fmaxf(fmaxf(sacc[mi][2][1], sacc[mi][2][2]), sacc[mi][2][3]);
      float a4 = fmaxf(fmaxf(sacc[mi][3][0], sacc[mi][3][1]), sacc[mi][3][2]);
      float b0 = fmaxf(fmaxf(a0, a1), a2);
      float b1 = fmaxf(fmaxf(a3, a4), sacc[mi][3][3]);
      float mt = fmaxf(b0, b1);
      mt = fmaxf(mt, __shfl_xor(mt, 16, 64));
      mt = fmaxf(mt, __shfl_xor(mt, 32, 64));
      if (mt > mrun[mi]){                       // exact defer: skip rescale when no growth
        float f_ = __builtin_amdgcn_exp2f(mrun[mi] - mt);
        mrun[mi] = mt;
        lrun[mi] *= f_;
#pragma unroll
        for (int di = 0; di < 4; ++di) oaccT[mi][di] = oaccT[mi][di] * f_;
      }
      const float mn = mrun[mi];
#pragma unroll
      for (int kk = 0; kk < 2; ++kk){
        union { unsigned u[4]; bf16x8 v; } pu;
#pragma unroll
        for (int h2 = 0; h2 < 2; ++h2){         // ni = 2kk + h2
          const int ni = 2*kk + h2;
          float p0 = __builtin_amdgcn_exp2f(sacc[mi][ni][0] - mn);
          float p1 = __builtin_amdgcn_exp2f(sacc[mi][ni][1] - mn);
          float p2 = __builtin_amdgcn_exp2f(sacc[mi][ni][2] - mn);
          float p3 = __builtin_amdgcn_exp2f(sacc[mi][ni][3] - mn);
          pu.u[2*h2    ] = pack_trunc(p0, p1);
          pu.u[2*h2 + 1] = pack_trunc(p2, p3);
        }
        pf[mi][kk] = pu.v;
      }
    }

    bf16x8 vf[4][2];                            // V^T frags (pi-permuted data, same addresses)
#pragma unroll
    for (int di = 0; di < 4; ++di)
#pragma unroll
      for (int kk = 0; kk < 2; ++kk){
        int row = di*16 + c15;
        vf[di][kk] = *reinterpret_cast<const bf16x8*>(bV + row*64 + ((((kk<<2)+g) ^ (row&7)) << 3));
      }

    // row sums + PV on the MFMA pipe (ones-sum is permutation-invariant)
    __builtin_amdgcn_s_setprio(1);
#pragma unroll
    for (int mi = 0; mi < 2; ++mi){
      f32x4 ls = mfma16(ones, pf[mi][0], vzero);
      ls = mfma16(ones, pf[mi][1], ls);
      lrun[mi] += ls[0];
    }
#pragma unroll
    for (int mi = 0; mi < 2; ++mi)
#pragma unroll
      for (int di = 0; di < 4; ++di){
        oaccT[mi][di] = mfma16(vf[di][0], pf[mi][0], oaccT[mi][di]);
        oaccT[mi][di] = mfma16(vf[di][1], pf[mi][1], oaccT[mi][di]);
      }
    __builtin_amdgcn_s_setprio(0);

    __syncthreads();                            // drains prefetch vmcnt + protects buffer swap
  }

  // normalize + write O [B,H,S,Dk]; lane c15=q, dk = di*16+g*4+r (RNE pack)
#pragma unroll
  for (int mi = 0; mi < 2; ++mi){
    float inv = 1.f / lrun[mi];
    int q = q0 + mi*16 + c15;
#pragma unroll
    for (int di = 0; di < 4; ++di){
      unsigned lo = pack2(oaccT[mi][di][0] * inv, oaccT[mi][di][1] * inv);
      unsigned hi = pack2(oaccT[mi][di][2] * inv, oaccT[mi][di][3] * inv);
      *reinterpret_cast<uint2*>(O + hb + ((size_t)q << 6) + di*16 + g*4) = make_uint2(lo, hi);
    }
  }
#undef STAGE_T
}

// ---------- launch ----------
extern "C" void kernel_launch(void* const* d_in, const int* in_sizes, int n_in,
                              void* d_out, int out_size, void* d_ws, size_t ws_size,
                              hipStream_t stream){
  const float* x  = (const float*)d_in[0];
  const float* wq = (const float*)d_in[1];
  const float* wk = (const float*)d_in[2];
  const float* wv = (const float*)d_in[3];
  const float* wo = (const float*)d_in[4];
  float* out = (float*)d_out;
  char* ws = (char*)d_ws;
  u16* xb  = (u16*)(ws);                    // 16 MB  x bf16 [8192][1024]
  u16* wqb = (u16*)(ws + (16u << 20));      // 2 MB  } contiguous [3072][1024]
  u16* wkb = (u16*)(ws + (18u << 20));      // 2 MB  }
  u16* wvb = (u16*)(ws + (20u << 20));      // 2 MB  }
  u16* wob = (u16*)(ws + (22u << 20));      // 2 MB
  u16* Qb  = (u16*)(ws + (24u << 20));      // 16 MB [B,H,S,Dk] pre-scaled 0.125*log2e
  u16* Kb  = (u16*)(ws + (40u << 20));      // 16 MB [B,H,S,Dk]
  u16* Vtb = (u16*)(ws + (56u << 20));      // 16 MB [B,H,Dk,S] pi-permuted per 64-tile
  u16* Ob  = (u16*)(ws + (72u << 20));      // 16 MB [B,H,S,Dk]

  cvt_all<<<12288, 256, 0, stream>>>(x, wq, wk, wv, wo, xb, wqb, wkb, wvb, wob);
  gemm_qkv<<<dim3(64, 24), 256, 0, stream>>>(xb, wqb, Qb, Kb, Vtb);
  attn_kernel<<<1024, 256, 0, stream>>>(Qb, Kb, Vtb, Ob);
  gemm_out<<<dim3(64, 8), 256, 0, stream>>>(Ob, wob, out);
}